// Round 1
// baseline (503.518 us; speedup 1.0000x reference)
//
#include <hip/hip_runtime.h>
#include <hip/hip_bf16.h>
#include <cstdint>

typedef __attribute__((ext_vector_type(8))) short short8;
typedef __attribute__((ext_vector_type(4))) short short4v;
typedef __attribute__((ext_vector_type(4))) float floatx4;

constexpr int B_ = 2, L_ = 4096, D_ = 1024, H_ = 16, DH = 64, F_ = 4096;
constexpr int M_ = B_ * L_;        // 8192 rows
constexpr int NQKV = 3 * D_;       // 3072
constexpr int VT_GUARD = 512;      // elements of guard before/after vt rows

// ---------------- workspace layout (bytes) ----------------
constexpr size_t OFF_XB  = 0;                                       // bf16 [M][D]
constexpr size_t OFF_WCT = OFF_XB  + (size_t)M_ * D_ * 2;           // bf16 [3072][1024]  (WqT|WkT|WvT)
constexpr size_t OFF_W1T = OFF_WCT + (size_t)NQKV * D_ * 2;         // bf16 [4096][1024]
constexpr size_t OFF_W2T = OFF_W1T + (size_t)F_ * D_ * 2;           // bf16 [1024][4096]
constexpr size_t OFF_QKV = OFF_W2T + (size_t)D_ * F_ * 2;           // bf16 [M][3072]
constexpr size_t OFF_VT  = OFF_QKV + (size_t)M_ * NQKV * 2;         // bf16 [B*H*64*L + 2*GUARD]
constexpr size_t OFF_ATT = OFF_VT  + ((size_t)B_*H_*DH*L_ + 2*VT_GUARD) * 2; // bf16 [M][D]
constexpr size_t OFF_HB  = OFF_ATT + (size_t)M_ * D_ * 2;           // bf16 [M][D] (post-LN h)
constexpr size_t OFF_MID = OFF_HB  + (size_t)M_ * D_ * 2;           // bf16 [M][F]
// total = OFF_MID + M*F*2  ~= 198 MB

static __device__ __forceinline__ float b2f(unsigned short u) {
    union { unsigned int i; float f; } v; v.i = ((unsigned int)u) << 16; return v.f;
}

static __device__ __forceinline__ void gload16(const void* g, void* l) {
    __builtin_amdgcn_global_load_lds(
        (const __attribute__((address_space(1))) uint32_t*)g,
        (__attribute__((address_space(3))) uint32_t*)l, 16, 0, 0);
}

// ---------------- f32 -> bf16 convert (x) ----------------
__global__ __launch_bounds__(256) void k_cvt_x(const float* __restrict__ x,
                                               __hip_bfloat16* __restrict__ xb) {
    int i = (blockIdx.x * 256 + threadIdx.x) * 8;
    float4 a = *(const float4*)(x + i);
    float4 b = *(const float4*)(x + i + 4);
    alignas(16) __hip_bfloat16 t[8];
    t[0] = __float2bfloat16(a.x); t[1] = __float2bfloat16(a.y);
    t[2] = __float2bfloat16(a.z); t[3] = __float2bfloat16(a.w);
    t[4] = __float2bfloat16(b.x); t[5] = __float2bfloat16(b.y);
    t[6] = __float2bfloat16(b.z); t[7] = __float2bfloat16(b.w);
    *(uint4*)(xb + i) = *(const uint4*)t;
}

// ---------------- transpose+convert: in [R][C] f32 -> out [C][R] bf16 ----------------
__global__ __launch_bounds__(256) void k_tcvt(const float* __restrict__ in,
                                              __hip_bfloat16* __restrict__ out,
                                              int R, int C) {
    __shared__ float t[64][65];
    int tx = threadIdx.x & 63, ty4 = threadIdx.x >> 6;
    int c0 = blockIdx.x * 64, r0 = blockIdx.y * 64;
#pragma unroll
    for (int i = 0; i < 16; i++) {
        int r = ty4 + i * 4;
        t[r][tx] = in[(size_t)(r0 + r) * C + c0 + tx];
    }
    __syncthreads();
#pragma unroll
    for (int i = 0; i < 16; i++) {
        int r = ty4 + i * 4;
        out[(size_t)(c0 + r) * R + r0 + tx] = __float2bfloat16(t[tx][r]);
    }
}

// ---------------- V transpose: qkv V-segment -> vt[bh*64+d][j] ----------------
__global__ __launch_bounds__(256) void k_vtrans(const __hip_bfloat16* __restrict__ qkv,
                                                __hip_bfloat16* __restrict__ vtg) {
    __shared__ __hip_bfloat16 t[64][72];
    int tx = threadIdx.x & 63, ty4 = threadIdx.x >> 6;
    int bh = blockIdx.y, b = bh >> 4, h = bh & 15;
    int j0 = blockIdx.x * 64;
#pragma unroll
    for (int i = 0; i < 16; i++) {
        int j = ty4 + i * 4;
        t[j][tx] = qkv[(size_t)(b * L_ + j0 + j) * NQKV + 2 * D_ + h * DH + tx];
    }
    __syncthreads();
#pragma unroll
    for (int i = 0; i < 16; i++) {
        int d = ty4 + i * 4;
        vtg[(long)(bh * DH + d) * L_ + j0 + tx] = t[tx][d];
    }
}

// ---------------- GEMM: C[M][N] = A[M][K](bf16) * BT[N][K](bf16)^T + epilogue ----------------
// EPI 0: +bias(seg3) -> bf16 qkv ; EPI 1: +bias, gelu -> bf16 mid ; EPI 2: +bias + h -> f32 out
template<int EPI>
__global__ __launch_bounds__(256, 2)
void k_gemm(const __hip_bfloat16* __restrict__ A, const __hip_bfloat16* __restrict__ BT,
            int M, int N, int K,
            const float* __restrict__ bias0, const float* __restrict__ bias1,
            const float* __restrict__ bias2,
            __hip_bfloat16* __restrict__ obf, float* __restrict__ of32,
            const __hip_bfloat16* __restrict__ hres) {
    __shared__ __hip_bfloat16 As[128 * 64];
    __shared__ __hip_bfloat16 Bs[128 * 64];
    const int tid = threadIdx.x, wave = tid >> 6, lane = tid & 63;
    const int m0 = blockIdx.x * 128, n0 = blockIdx.y * 128;
    const int wr = wave >> 1, wc = wave & 1;
    const int lo = lane & 15, hi = lane >> 4;
    floatx4 acc[4][4] = {};

    for (int kt = 0; kt < K; kt += 64) {
        __syncthreads();
#pragma unroll
        for (int i = 0; i < 4; i++) {
            int chunk = i * 256 + tid;
            const __hip_bfloat16* ga = A + (size_t)(m0 + (chunk >> 3)) * K + kt + (chunk & 7) * 8;
            gload16(ga, As + (size_t)(i * 256 + wave * 64) * 8);
            const __hip_bfloat16* gb = BT + (size_t)(n0 + (chunk >> 3)) * K + kt + (chunk & 7) * 8;
            gload16(gb, Bs + (size_t)(i * 256 + wave * 64) * 8);
        }
        __syncthreads();
#pragma unroll
        for (int kk = 0; kk < 2; kk++) {
            short8 af[4], bf[4];
#pragma unroll
            for (int mt = 0; mt < 4; mt++)
                af[mt] = *(const short8*)(As + (wr * 64 + mt * 16 + lo) * 64 + kk * 32 + hi * 8);
#pragma unroll
            for (int nt = 0; nt < 4; nt++)
                bf[nt] = *(const short8*)(Bs + (wc * 64 + nt * 16 + lo) * 64 + kk * 32 + hi * 8);
#pragma unroll
            for (int mt = 0; mt < 4; mt++)
#pragma unroll
                for (int nt = 0; nt < 4; nt++)
                    acc[mt][nt] = __builtin_amdgcn_mfma_f32_16x16x32_bf16(af[mt], bf[nt], acc[mt][nt], 0, 0, 0);
        }
    }

#pragma unroll
    for (int mt = 0; mt < 4; mt++) {
#pragma unroll
        for (int nt = 0; nt < 4; nt++) {
            int col = n0 + wc * 64 + nt * 16 + lo;
#pragma unroll
            for (int r = 0; r < 4; r++) {
                int row = m0 + wr * 64 + mt * 16 + hi * 4 + r;
                float v = acc[mt][nt][r];
                if (EPI == 0) {
                    float bia = (col < 1024) ? bias0[col]
                              : (col < 2048 ? bias1[col - 1024] : bias2[col - 2048]);
                    obf[(size_t)row * NQKV + col] = __float2bfloat16(v + bia);
                } else if (EPI == 1) {
                    v += bias0[col];
                    v = 0.5f * v * (1.0f + erff(v * 0.70710678118654752440f));
                    obf[(size_t)row * F_ + col] = __float2bfloat16(v);
                } else {
                    v += bias0[col];
                    v += b2f(*(const unsigned short*)&hres[(size_t)row * D_ + col]);
                    of32[(size_t)row * D_ + col] = v;
                }
            }
        }
    }
}

// ---------------- sliding-window attention ----------------
// grid (L/64, B*H); 4 waves, each wave owns 16 query rows; window = +-128
__global__ __launch_bounds__(256, 2)
void k_attn(const __hip_bfloat16* __restrict__ qkv, const float* __restrict__ mask,
            const __hip_bfloat16* __restrict__ vtg, __hip_bfloat16* __restrict__ attnb) {
    constexpr int PS = 296;                 // padded P row stride (elems)
    __shared__ __hip_bfloat16 P[4][16 * PS];
    const int tid = threadIdx.x, wave = tid >> 6, lane = tid & 63;
    const int bh = blockIdx.y, b = bh >> 4, h = bh & 15;
    const int q0 = blockIdx.x * 64 + wave * 16;
    const int lo = lane & 15, hi = lane >> 4;

    // Q fragments (A operand): row = lo, k-chunk = hi*8
    short8 qf0, qf1;
    {
        const __hip_bfloat16* qb = qkv + (size_t)(b * L_ + q0 + lo) * NQKV + h * DH + hi * 8;
        qf0 = *(const short8*)qb;
        qf1 = *(const short8*)(qb + 32);
    }

    floatx4 sc[17];
    const __hip_bfloat16* kcol = qkv + (size_t)b * L_ * NQKV + D_ + h * DH + hi * 8;
#pragma unroll
    for (int t = 0; t < 17; t++) {
        int jg = q0 - 128 + t * 16 + lo;
        int jc = jg < 0 ? 0 : (jg >= L_ ? L_ - 1 : jg);
        const __hip_bfloat16* kb = kcol + (size_t)jc * NQKV;
        short8 kf0 = *(const short8*)kb;
        short8 kf1 = *(const short8*)(kb + 32);
        floatx4 a = {};
        a = __builtin_amdgcn_mfma_f32_16x16x32_bf16(qf0, kf0, a, 0, 0, 0);
        a = __builtin_amdgcn_mfma_f32_16x16x32_bf16(qf1, kf1, a, 0, 0, 0);
        float mval = mask[b * L_ + jc];
        bool jok = (jg >= 0) && (jg < L_) && (mval == 0.0f);
#pragma unroll
        for (int r = 0; r < 4; r++) {
            int qi = q0 + hi * 4 + r;
            bool ok = jok && (jg >= qi - 128) && (jg <= qi + 128);
            a[r] = ok ? a[r] * 0.125f : -1e9f;
        }
        sc[t] = a;
    }

    // softmax along j (spread over lo within 16-lane groups)
#pragma unroll
    for (int r = 0; r < 4; r++) {
        float m = -3e38f;
#pragma unroll
        for (int t = 0; t < 17; t++) m = fmaxf(m, sc[t][r]);
        m = fmaxf(m, __shfl_xor(m, 1));
        m = fmaxf(m, __shfl_xor(m, 2));
        m = fmaxf(m, __shfl_xor(m, 4));
        m = fmaxf(m, __shfl_xor(m, 8));
        float s = 0.0f;
#pragma unroll
        for (int t = 0; t < 17; t++) { float e = __expf(sc[t][r] - m); sc[t][r] = e; s += e; }
        s += __shfl_xor(s, 1); s += __shfl_xor(s, 2);
        s += __shfl_xor(s, 4); s += __shfl_xor(s, 8);
        float inv = 1.0f / s;
#pragma unroll
        for (int t = 0; t < 17; t++) sc[t][r] *= inv;
    }

    // write P (transpose through LDS): P[p][j], p = hi*4+r, j = t*16+lo
    __hip_bfloat16* Pw = &P[wave][0];
#pragma unroll
    for (int t = 0; t < 17; t++)
#pragma unroll
        for (int r = 0; r < 4; r++)
            Pw[(hi * 4 + r) * PS + t * 16 + lo] = __float2bfloat16(sc[t][r]);
    // zero tail tile (cols 272..287) so the 9th K=32 PV step contributes 0
    {
        int zr = lane >> 2, zc = 272 + (lane & 3) * 4;
        __hip_bfloat16 z = __float2bfloat16(0.0f);
#pragma unroll
        for (int i = 0; i < 4; i++) Pw[zr * PS + zc + i] = z;
    }

    // PV: o[p][d] = sum_j P[p][j] * V[j][d]   (B operand from V^T rows)
    floatx4 o[4] = {};
#pragma unroll
    for (int st = 0; st < 9; st++) {
        short8 pa = *(const short8*)(Pw + lo * PS + st * 32 + hi * 8);
        int jb = q0 - 128 + st * 32 + hi * 8;
#pragma unroll
        for (int dt = 0; dt < 4; dt++) {
            const __hip_bfloat16* vb = vtg + (long)(bh * DH + dt * 16 + lo) * L_ + jb;
            short8 vf = *(const short8*)vb;
            o[dt] = __builtin_amdgcn_mfma_f32_16x16x32_bf16(pa, vf, o[dt], 0, 0, 0);
        }
    }

#pragma unroll
    for (int dt = 0; dt < 4; dt++)
#pragma unroll
        for (int r = 0; r < 4; r++) {
            int row = q0 + hi * 4 + r;
            attnb[(size_t)(b * L_ + row) * D_ + h * DH + dt * 16 + lo] =
                __float2bfloat16(o[dt][r]);
        }
}

// ---------------- residual + LayerNorm -> hb (bf16) ----------------
__global__ __launch_bounds__(256)
void k_ln(const float* __restrict__ x, const __hip_bfloat16* __restrict__ attnb,
          const float* __restrict__ g, const float* __restrict__ bt,
          __hip_bfloat16* __restrict__ hb) {
    const int row = blockIdx.x, tid = threadIdx.x;
    const int c4 = tid * 4;
    float4 xv = *(const float4*)(x + (size_t)row * D_ + c4);
    short4v av = *(const short4v*)(attnb + (size_t)row * D_ + c4);
    float h0 = xv.x + b2f((unsigned short)av[0]);
    float h1 = xv.y + b2f((unsigned short)av[1]);
    float h2 = xv.z + b2f((unsigned short)av[2]);
    float h3 = xv.w + b2f((unsigned short)av[3]);
    float s = h0 + h1 + h2 + h3;
    float q = h0 * h0 + h1 * h1 + h2 * h2 + h3 * h3;
#pragma unroll
    for (int off = 32; off > 0; off >>= 1) {
        s += __shfl_down(s, off);
        q += __shfl_down(q, off);
    }
    __shared__ float red[8];
    int wave = tid >> 6, lane = tid & 63;
    if (lane == 0) { red[wave] = s; red[4 + wave] = q; }
    __syncthreads();
    s = red[0] + red[1] + red[2] + red[3];
    q = red[4] + red[5] + red[6] + red[7];
    float mu = s * (1.0f / D_);
    float var = q * (1.0f / D_) - mu * mu;
    float inv = rsqrtf(var + 1e-5f);
    float4 gv = *(const float4*)(g + c4);
    float4 bv = *(const float4*)(bt + c4);
    alignas(8) __hip_bfloat16 ov[4];
    ov[0] = __float2bfloat16((h0 - mu) * inv * gv.x + bv.x);
    ov[1] = __float2bfloat16((h1 - mu) * inv * gv.y + bv.y);
    ov[2] = __float2bfloat16((h2 - mu) * inv * gv.z + bv.z);
    ov[3] = __float2bfloat16((h3 - mu) * inv * gv.w + bv.w);
    *(short4v*)(hb + (size_t)row * D_ + c4) = *(const short4v*)ov;
}

// ---------------- launch ----------------
extern "C" void kernel_launch(void* const* d_in, const int* in_sizes, int n_in,
                              void* d_out, int out_size, void* d_ws, size_t ws_size,
                              hipStream_t stream) {
    const float* x    = (const float*)d_in[0];
    const float* mask = (const float*)d_in[1];
    const float* Wq   = (const float*)d_in[2];
    const float* bq   = (const float*)d_in[3];
    const float* Wk   = (const float*)d_in[4];
    const float* bk   = (const float*)d_in[5];
    const float* Wv   = (const float*)d_in[6];
    const float* bv   = (const float*)d_in[7];
    const float* ln_g = (const float*)d_in[8];
    const float* ln_b = (const float*)d_in[9];
    const float* W1   = (const float*)d_in[10];
    const float* b1   = (const float*)d_in[11];
    const float* W2   = (const float*)d_in[12];
    const float* b2   = (const float*)d_in[13];
    float* out = (float*)d_out;
    char* ws = (char*)d_ws;

    __hip_bfloat16* xb   = (__hip_bfloat16*)(ws + OFF_XB);
    __hip_bfloat16* wct  = (__hip_bfloat16*)(ws + OFF_WCT);
    __hip_bfloat16* w1t  = (__hip_bfloat16*)(ws + OFF_W1T);
    __hip_bfloat16* w2t  = (__hip_bfloat16*)(ws + OFF_W2T);
    __hip_bfloat16* qkvb = (__hip_bfloat16*)(ws + OFF_QKV);
    __hip_bfloat16* vtg  = (__hip_bfloat16*)(ws + OFF_VT) + VT_GUARD;
    __hip_bfloat16* attb = (__hip_bfloat16*)(ws + OFF_ATT);
    __hip_bfloat16* hb   = (__hip_bfloat16*)(ws + OFF_HB);
    __hip_bfloat16* midb = (__hip_bfloat16*)(ws + OFF_MID);

    // input conversions
    k_cvt_x<<<(M_ * D_) / 2048, 256, 0, stream>>>(x, xb);
    k_tcvt<<<dim3(D_ / 64, D_ / 64), 256, 0, stream>>>(Wq, wct,                 D_, D_);
    k_tcvt<<<dim3(D_ / 64, D_ / 64), 256, 0, stream>>>(Wk, wct + 1024 * 1024,   D_, D_);
    k_tcvt<<<dim3(D_ / 64, D_ / 64), 256, 0, stream>>>(Wv, wct + 2 * 1024 * 1024, D_, D_);
    k_tcvt<<<dim3(F_ / 64, D_ / 64), 256, 0, stream>>>(W1, w1t, D_, F_);
    k_tcvt<<<dim3(D_ / 64, F_ / 64), 256, 0, stream>>>(W2, w2t, F_, D_);

    // fused QKV projection
    k_gemm<0><<<dim3(M_ / 128, NQKV / 128), 256, 0, stream>>>(
        xb, wct, M_, NQKV, D_, bq, bk, bv, qkvb, nullptr, nullptr);

    // V transpose, attention
    k_vtrans<<<dim3(L_ / 64, B_ * H_), 256, 0, stream>>>(qkvb, vtg);
    k_attn<<<dim3(L_ / 64, B_ * H_), 256, 0, stream>>>(qkvb, mask, vtg, attb);

    // residual + LN
    k_ln<<<M_, 256, 0, stream>>>(x, attb, ln_g, ln_b, hb);

    // MLP
    k_gemm<1><<<dim3(M_ / 128, F_ / 128), 256, 0, stream>>>(
        hb, w1t, M_, F_, D_, b1, nullptr, nullptr, midb, nullptr, nullptr);
    k_gemm<2><<<dim3(M_ / 128, D_ / 128), 256, 0, stream>>>(
        midb, w2t, M_, D_, F_, b2, nullptr, nullptr, nullptr, out, hb);
}